// Round 17
// baseline (586.254 us; speedup 1.0000x reference)
//
#include <hip/hip_runtime.h>
#include <hip/hip_bf16.h>

// MoE Experts v16: BOTH GEMMs = 128x128-tile transplant of the proven v12-g2
// deep-pipe loop (3-buf ring, counted vmcnt(4) for 4-load stages, involution
// swizzle, setprio, split A/B staging). 48KB LDS -> 3 blocks/CU; exact grid
// quantization (g1 4608 = 6x768, g2 2304 = 3x768). Schedule-rewrite lane
// closed (v13/v14/v15 post-mortem: plateau is block-level stall convoying).

#define T_TOK   8192
#define D_MODEL 1024
#define D_FF    4096
#define NE      8
#define MT128   144                // 128-row tiles (256-aligned expert pad)
#define ROWS_MAX (MT128 * 128)     // 18432
#define BUFX    16384              // per-buffer: A 8KB + B 8KB
#define LDS_GX  49152              // 3 buffers

typedef float f32x4 __attribute__((ext_vector_type(4)));
typedef short s16x8 __attribute__((ext_vector_type(8)));
typedef short s16x4 __attribute__((ext_vector_type(4)));
typedef unsigned short u16;

__device__ __forceinline__ u16 f2bf(float x) {
  __hip_bfloat16 h = __float2bfloat16(x);   // RNE
  return *reinterpret_cast<u16*>(&h);
}

__device__ __forceinline__ s16x8 cvt8(float4 a, float4 b) {
  s16x8 v;
  v[0] = (short)f2bf(a.x); v[1] = (short)f2bf(a.y);
  v[2] = (short)f2bf(a.z); v[3] = (short)f2bf(a.w);
  v[4] = (short)f2bf(b.x); v[5] = (short)f2bf(b.y);
  v[6] = (short)f2bf(b.z); v[7] = (short)f2bf(b.w);
  return v;
}

__device__ __forceinline__ void gload_lds16(const void* g, void* l) {
  __builtin_amdgcn_global_load_lds((const __attribute__((address_space(1))) void*)g,
                                   (__attribute__((address_space(3))) void*)l,
                                   16, 0, 0);
}

// ---------------- routing compaction ----------------
__global__ void moe_route(const int* __restrict__ sel, const float* __restrict__ rw,
                          int* __restrict__ cnt, int* __restrict__ tidx,
                          float* __restrict__ tw) {
  int t = blockIdx.x * blockDim.x + threadIdx.x;
  if (t >= T_TOK) return;
  int e0 = 0, e1 = 0;
  #pragma unroll
  for (int e = 0; e < NE; ++e) {
    if (sel[t * 16 + e])     e0 = e;
    if (sel[t * 16 + 8 + e]) e1 = e;
  }
  float w0 = rw[2 * t], w1 = rw[2 * t + 1];
  if (e0 == e1) {
    int p = atomicAdd(&cnt[e0], 1);
    tidx[e0 * T_TOK + p] = t; tw[e0 * T_TOK + p] = w0 + w1;
  } else {
    int p = atomicAdd(&cnt[e0], 1);
    tidx[e0 * T_TOK + p] = t; tw[e0 * T_TOK + p] = w0;
    int q = atomicAdd(&cnt[e1], 1);
    tidx[e1 * T_TOK + q] = t; tw[e1 * T_TOK + q] = w1;
  }
}

// ---------------- tile map: 256-aligned segments, 128-tile index ------------
__global__ void moe_tilemap(const int* __restrict__ cnt, const int* __restrict__ tidx,
                            const float* __restrict__ tw, int* __restrict__ te128,
                            int* __restrict__ tokr, float* __restrict__ wr) {
  int off[NE + 1];
  {
    int o = 0;
    #pragma unroll
    for (int e = 0; e < NE; ++e) { off[e] = o; o += (cnt[e] + 255) & ~255; }
    off[NE] = o;
  }
  const int total = off[NE];
  const int gid = blockIdx.x * blockDim.x + threadIdx.x;
  const int stride = gridDim.x * blockDim.x;
  for (int t = gid; t < MT128; t += stride) {
    int r0 = t * 128; int e = -1;
    if (r0 < total) {
      #pragma unroll
      for (int i = NE - 1; i >= 0; --i) if (r0 >= off[i]) { e = i; break; }
    }
    te128[t] = e;
  }
  for (int i = gid; i < ROWS_MAX; i += stride) {
    if (i >= total) { tokr[i] = -1; wr[i] = 0.f; continue; }
    int e = 0;
    #pragma unroll
    for (int k = NE - 1; k >= 0; --k) if (i >= off[k]) { e = k; break; }
    int j = i - off[e];
    int ok = j < cnt[e];
    tokr[i] = ok ? tidx[e * T_TOK + j] : -1;
    wr[i]   = ok ? tw[e * T_TOK + j] : 0.f;
  }
}

// ---------------- gather X rows -> bf16 Xg ----------------
__global__ void moe_gather_x(const float* __restrict__ hs, const int* __restrict__ tokr,
                             u16* __restrict__ Xg) {
  int row = blockIdx.x;
  int tok = tokr[row];
  int c = threadIdx.x * 4;
  u16* dst = Xg + (size_t)row * D_MODEL + c;
  s16x4 o;
  if (tok < 0) {
    o[0] = o[1] = o[2] = o[3] = 0;
  } else {
    float4 v = *(const float4*)(hs + (size_t)tok * D_MODEL + c);
    o[0] = (short)f2bf(v.x); o[1] = (short)f2bf(v.y);
    o[2] = (short)f2bf(v.z); o[3] = (short)f2bf(v.w);
  }
  *(s16x4*)dst = o;
}

// ---------------- f32 -> bf16 weight converts ----------------
__global__ void moe_cvt_w(const float* __restrict__ wi, const float* __restrict__ wo,
                          u16* __restrict__ wib, u16* __restrict__ wob) {
  const size_t NW = (size_t)NE * D_FF * D_MODEL;
  size_t i = ((size_t)blockIdx.x * blockDim.x + threadIdx.x) * 8;
  const float* src; u16* dst;
  if (i < NW) { src = wi + i; dst = wib + i; }
  else        { src = wo + (i - NW); dst = wob + (i - NW); }
  float4 a = *(const float4*)(src);
  float4 b = *(const float4*)(src + 4);
  *(s16x8*)dst = cvt8(a, b);
}

__global__ void moe_cvt_wi_s(const float* __restrict__ wi, u16* __restrict__ wis,
                             int W, int f0) {
  size_t i = ((size_t)blockIdx.x * blockDim.x + threadIdx.x) * 8;
  size_t per = (size_t)W * D_MODEL;
  int e = (int)(i / per); size_t r = i % per;
  const float* src = wi + ((size_t)e * D_FF + f0) * D_MODEL + r;
  float4 a = *(const float4*)src;
  float4 b = *(const float4*)(src + 4);
  *(s16x8*)(wis + i) = cvt8(a, b);
}

__global__ void moe_cvt_wo_s(const float* __restrict__ wo, u16* __restrict__ wos,
                             int W, int f0) {
  size_t i = ((size_t)blockIdx.x * blockDim.x + threadIdx.x) * 8;
  size_t per = (size_t)D_MODEL * W;
  int e = (int)(i / per); size_t r = i % per;
  int row = (int)(r / W), col = (int)(r % W);
  const float* src = wo + ((size_t)e * D_MODEL + row) * D_FF + f0 + col;
  float4 a = *(const float4*)src;
  float4 b = *(const float4*)(src + 4);
  *(s16x8*)(wos + i) = cvt8(a, b);
}

#define MM4(mi, a) \
  acc[mi][0] = __builtin_amdgcn_mfma_f32_16x16x32_bf16(a, bq0, acc[mi][0], 0, 0, 0); \
  acc[mi][1] = __builtin_amdgcn_mfma_f32_16x16x32_bf16(a, bq1, acc[mi][1], 0, 0, 0); \
  acc[mi][2] = __builtin_amdgcn_mfma_f32_16x16x32_bf16(a, bq2, acc[mi][2], 0, 0, 0); \
  acc[mi][3] = __builtin_amdgcn_mfma_f32_16x16x32_bf16(a, bq3, acc[mi][3], 0, 0, 0);

// ---------------- GEMM1: 128x128 deep-pipe, H = relu(Xg @ Wi^T) -------------
// 256 thr / 4 waves (2Mx2N), per-wave 64x64, BK=32, 3x16KB bufs, vmcnt(4).
template <bool FULL>
__global__ __launch_bounds__(256, 3)
void moe_g1(const u16* __restrict__ Xg, const u16* __restrict__ wiP,
            const int* __restrict__ te128, u16* __restrict__ H,
            int W, int f0) {
  extern __shared__ char lds[];
  const int GR = gridDim.x;
  const int task = (blockIdx.x & 7) * (GR >> 3) + (blockIdx.x >> 3);
  const int mt = task % MT128;
  const int nc = task / MT128;
  const int e = te128[mt];
  if (e < 0) return;
  const int grow0 = mt * 128;
  const int fcol = nc * 128;

  const int tid = threadIdx.x;
  const int lane = tid & 63, wv = tid >> 6;
  const int lg = lane >> 4, ll = lane & 15;
  const int wm = wv >> 1, wn = wv & 1;

  const int sw = (tid * 16) ^ (((tid >> 3) & 7) << 4);
  const int srow = sw >> 6, scol = sw & 63;           // srow in [0,64)
  const int inner = (ll * 64 + lg * 16) ^ (((ll >> 1) & 7) << 4);

  const char* gA = (const char*)(Xg + (size_t)grow0 * D_MODEL);
  const char* gB = (const char*)(wiP + (FULL ? ((size_t)e * D_FF + f0 + fcol)
                                             : ((size_t)e * W + fcol)) * D_MODEL);

  f32x4 acc[4][4];
  #pragma unroll
  for (int m = 0; m < 4; ++m)
    #pragma unroll
    for (int n = 0; n < 4; ++n) acc[m][n] = (f32x4){0.f, 0.f, 0.f, 0.f};

  auto stageA = [&](int kb, char* lbuf) {
    #pragma unroll
    for (int j = 0; j < 2; ++j)
      gload_lds16(gA + (size_t)(j * 64 + srow) * 2048 + kb + scol,
                  lbuf + j * 4096 + tid * 16);
  };
  auto stageB = [&](int kb, char* lbuf) {
    #pragma unroll
    for (int j = 0; j < 2; ++j)
      gload_lds16(gB + (size_t)(j * 64 + srow) * 2048 + kb + scol,
                  lbuf + 8192 + j * 4096 + tid * 16);
  };

  const int NT = D_MODEL / 32;
  stageA(0, lds);   stageB(0, lds);
  stageA(64, lds + BUFX); stageB(64, lds + BUFX);
  int bufi = 0;
  for (int t = 0; t < NT; ++t) {
    if (t < NT - 1) { asm volatile("s_waitcnt vmcnt(4)" ::: "memory"); }
    else            { asm volatile("s_waitcnt vmcnt(0)" ::: "memory"); }
    asm volatile("s_barrier" ::: "memory");
    const char* la = lds + bufi * BUFX + wm * 4096;
    const char* lb = lds + bufi * BUFX + 8192 + wn * 4096;
    int b2 = bufi + 2; if (b2 >= 3) b2 -= 3;
    const bool pf = (t + 2 < NT);
    s16x8 bq0 = *(const s16x8*)(lb + 0 * 1024 + inner);
    s16x8 bq1 = *(const s16x8*)(lb + 1 * 1024 + inner);
    s16x8 bq2 = *(const s16x8*)(lb + 2 * 1024 + inner);
    s16x8 bq3 = *(const s16x8*)(lb + 3 * 1024 + inner);
    {
      s16x8 a0 = *(const s16x8*)(la + 0 * 1024 + inner);
      s16x8 a1 = *(const s16x8*)(la + 1 * 1024 + inner);
      if (pf) stageA((t + 2) * 64, lds + b2 * BUFX);
      __builtin_amdgcn_s_setprio(1);
      MM4(0, a0) MM4(1, a1)
      __builtin_amdgcn_s_setprio(0);
    }
    {
      s16x8 a2 = *(const s16x8*)(la + 2 * 1024 + inner);
      s16x8 a3 = *(const s16x8*)(la + 3 * 1024 + inner);
      if (pf) stageB((t + 2) * 64, lds + b2 * BUFX);
      __builtin_amdgcn_s_setprio(1);
      MM4(2, a2) MM4(3, a3)
      __builtin_amdgcn_s_setprio(0);
    }
    bufi += 1; if (bufi >= 3) bufi -= 3;
  }

  #pragma unroll
  for (int mf = 0; mf < 4; ++mf) {
    #pragma unroll
    for (int r = 0; r < 4; ++r) {
      int row = grow0 + wm * 64 + mf * 16 + lg * 4 + r;
      u16* hp = H + (size_t)row * W + fcol + wn * 64 + ll;
      #pragma unroll
      for (int nf = 0; nf < 4; ++nf) {
        float v = acc[mf][nf][r];
        hp[nf * 16] = f2bf(v > 0.f ? v : 0.f);
      }
    }
  }
}

// ---------------- GEMM2: 128x128 deep-pipe, out += w.*(H @ Wo^T) ------------
// task = dc + 8*(mt + MT128*kc), dc innermost (H L2 reuse); atomic scatter.
template <bool FULL>
__global__ __launch_bounds__(256, 3)
void moe_g2(const u16* __restrict__ H, const u16* __restrict__ woP,
            const int* __restrict__ te128, const int* __restrict__ tokr,
            const float* __restrict__ wr, float* __restrict__ out,
            int W, int f0, int KCH) {
  extern __shared__ char lds[];
  const int GR = gridDim.x;
  const int task = (blockIdx.x & 7) * (GR >> 3) + (blockIdx.x >> 3);
  const int dc = task & 7;
  const int rest = task >> 3;
  const int mt = rest % MT128;
  const int kc = rest / MT128;
  const int e = te128[mt];
  if (e < 0) return;
  const int grow0 = mt * 128;
  const int dcol0 = dc * 128;

  const int tid = threadIdx.x;
  const int lane = tid & 63, wv = tid >> 6;
  const int lg = lane >> 4, ll = lane & 15;
  const int wm = wv >> 1, wn = wv & 1;

  const int sw = (tid * 16) ^ (((tid >> 3) & 7) << 4);
  const int srow = sw >> 6, scol = sw & 63;
  const int inner = (ll * 64 + lg * 16) ^ (((ll >> 1) & 7) << 4);

  const size_t pA = (size_t)W * 2;
  const size_t pB = (FULL ? (size_t)D_FF : (size_t)W) * 2;
  const char* gA = (const char*)(H + (size_t)grow0 * W) + (size_t)kc * KCH * 2;
  const char* gB = (const char*)(woP + ((size_t)e * D_MODEL + dcol0) * (pB / 2)
                                 + (FULL ? f0 : 0)) + (size_t)kc * KCH * 2;

  f32x4 acc[4][4];
  #pragma unroll
  for (int m = 0; m < 4; ++m)
    #pragma unroll
    for (int n = 0; n < 4; ++n) acc[m][n] = (f32x4){0.f, 0.f, 0.f, 0.f};

  auto stageA = [&](int kb, char* lbuf) {
    #pragma unroll
    for (int j = 0; j < 2; ++j)
      gload_lds16(gA + (size_t)(j * 64 + srow) * pA + kb + scol,
                  lbuf + j * 4096 + tid * 16);
  };
  auto stageB = [&](int kb, char* lbuf) {
    #pragma unroll
    for (int j = 0; j < 2; ++j)
      gload_lds16(gB + (size_t)(j * 64 + srow) * pB + kb + scol,
                  lbuf + 8192 + j * 4096 + tid * 16);
  };

  const int NT = KCH / 32;
  stageA(0, lds);   stageB(0, lds);
  stageA(64, lds + BUFX); stageB(64, lds + BUFX);
  int bufi = 0;
  for (int t = 0; t < NT; ++t) {
    if (t < NT - 1) { asm volatile("s_waitcnt vmcnt(4)" ::: "memory"); }
    else            { asm volatile("s_waitcnt vmcnt(0)" ::: "memory"); }
    asm volatile("s_barrier" ::: "memory");
    const char* la = lds + bufi * BUFX + wm * 4096;
    const char* lb = lds + bufi * BUFX + 8192 + wn * 4096;
    int b2 = bufi + 2; if (b2 >= 3) b2 -= 3;
    const bool pf = (t + 2 < NT);
    s16x8 bq0 = *(const s16x8*)(lb + 0 * 1024 + inner);
    s16x8 bq1 = *(const s16x8*)(lb + 1 * 1024 + inner);
    s16x8 bq2 = *(const s16x8*)(lb + 2 * 1024 + inner);
    s16x8 bq3 = *(const s16x8*)(lb + 3 * 1024 + inner);
    {
      s16x8 a0 = *(const s16x8*)(la + 0 * 1024 + inner);
      s16x8 a1 = *(const s16x8*)(la + 1 * 1024 + inner);
      if (pf) stageA((t + 2) * 64, lds + b2 * BUFX);
      __builtin_amdgcn_s_setprio(1);
      MM4(0, a0) MM4(1, a1)
      __builtin_amdgcn_s_setprio(0);
    }
    {
      s16x8 a2 = *(const s16x8*)(la + 2 * 1024 + inner);
      s16x8 a3 = *(const s16x8*)(la + 3 * 1024 + inner);
      if (pf) stageB((t + 2) * 64, lds + b2 * BUFX);
      __builtin_amdgcn_s_setprio(1);
      MM4(2, a2) MM4(3, a3)
      __builtin_amdgcn_s_setprio(0);
    }
    bufi += 1; if (bufi >= 3) bufi -= 3;
  }

  #pragma unroll
  for (int mf = 0; mf < 4; ++mf) {
    #pragma unroll
    for (int r = 0; r < 4; ++r) {
      int row = grow0 + wm * 64 + mf * 16 + lg * 4 + r;
      int tok = tokr[row];
      if (tok >= 0) {
        float w = wr[row];
        float* op = out + (size_t)tok * D_MODEL + dcol0 + wn * 64 + ll;
        #pragma unroll
        for (int nf = 0; nf < 4; ++nf)
          atomicAdd(op + nf * 16, acc[mf][nf][r] * w);
      }
    }
  }
}

// ---------------- host ----------------
extern "C" void kernel_launch(void* const* d_in, const int* in_sizes, int n_in,
                              void* d_out, int out_size, void* d_ws, size_t ws_size,
                              hipStream_t stream) {
  const float* hs  = (const float*)d_in[0];
  const int*   sel = (const int*)d_in[1];
  const float* rw  = (const float*)d_in[2];
  const float* wi  = (const float*)d_in[3];
  const float* wo  = (const float*)d_in[4];
  float* out = (float*)d_out;

  const size_t NW   = (size_t)NE * D_FF * D_MODEL;
  const size_t CTRL = 1u << 20;
  const size_t WB   = 2 * NW * sizeof(u16);
  const size_t XGB  = (size_t)ROWS_MAX * D_MODEL * 2;

  bool FULLW = true; int W = D_FF;
  {
    bool found = false;
    for (int f : {1, 2, 4, 8, 16}) {
      int Wc = D_FF / f;
      size_t need = CTRL + WB + XGB + (size_t)ROWS_MAX * Wc * 2;
      if (need <= ws_size) { FULLW = true; W = Wc; found = true; break; }
    }
    if (!found) {
      for (int Wc : {1024, 512, 256}) {
        size_t sl = (size_t)2 * NE * Wc * D_MODEL * 2;
        size_t need = CTRL + sl + XGB + (size_t)ROWS_MAX * Wc * 2;
        if (need <= ws_size) { FULLW = false; W = Wc; break; }
      }
    }
  }
  const int FS = D_FF / W;

  size_t off = 0;
  auto take = [&](size_t b) -> char* {
    char* r = (char*)d_ws + off; off = (off + b + 255) & ~(size_t)255; return r;
  };
  int*   tidx = (int*)take((size_t)NE * T_TOK * 4);
  float* tw   = (float*)take((size_t)NE * T_TOK * 4);
  int*   tokr = (int*)take((size_t)ROWS_MAX * 4);
  float* wrr  = (float*)take((size_t)ROWS_MAX * 4);
  int*   te   = (int*)take(MT128 * 4);
  int*   cnt  = (int*)take(256);
  off = CTRL;
  u16 *wiP, *woP;
  if (FULLW) { wiP = (u16*)take(NW * 2); woP = (u16*)take(NW * 2); }
  else       { wiP = (u16*)take((size_t)NE * W * D_MODEL * 2);
               woP = (u16*)take((size_t)NE * D_MODEL * W * 2); }
  u16* Xg   = (u16*)take(XGB);
  u16* Hbuf = (u16*)take((size_t)ROWS_MAX * W * 2);

  hipMemsetAsync(cnt, 0, 256, stream);
  hipMemsetAsync(d_out, 0, (size_t)out_size * sizeof(float), stream);
  moe_route<<<T_TOK / 256, 256, 0, stream>>>(sel, rw, cnt, tidx, tw);
  moe_tilemap<<<64, 256, 0, stream>>>(cnt, tidx, tw, te, tokr, wrr);
  moe_gather_x<<<ROWS_MAX, 256, 0, stream>>>(hs, tokr, Xg);
  if (FULLW)
    moe_cvt_w<<<(int)(2 * NW / 8 / 256), 256, 0, stream>>>(wi, wo, wiP, woP);

  hipFuncSetAttribute(reinterpret_cast<const void*>(&moe_g1<true>),
                      hipFuncAttributeMaxDynamicSharedMemorySize, LDS_GX);
  hipFuncSetAttribute(reinterpret_cast<const void*>(&moe_g1<false>),
                      hipFuncAttributeMaxDynamicSharedMemorySize, LDS_GX);
  hipFuncSetAttribute(reinterpret_cast<const void*>(&moe_g2<true>),
                      hipFuncAttributeMaxDynamicSharedMemorySize, LDS_GX);
  hipFuncSetAttribute(reinterpret_cast<const void*>(&moe_g2<false>),
                      hipFuncAttributeMaxDynamicSharedMemorySize, LDS_GX);

  const int KCH = W / 2;                          // kc in {0,1}
  const int g1grid = MT128 * (W / 128);           // 4608 at FS=1
  const int g2grid = MT128 * 8 * 2;               // 2304
  const int cvtblk = (int)(((size_t)NE * W * D_MODEL / 8) / 256);

  for (int p = 0; p < FS; ++p) {
    const int f0 = p * W;
    if (!FULLW) {
      moe_cvt_wi_s<<<cvtblk, 256, 0, stream>>>(wi, wiP, W, f0);
      moe_cvt_wo_s<<<cvtblk, 256, 0, stream>>>(wo, woP, W, f0);
    }
    if (FULLW) {
      moe_g1<true><<<g1grid, 256, LDS_GX, stream>>>(Xg, wiP, te, Hbuf, W, f0);
      moe_g2<true><<<g2grid, 256, LDS_GX, stream>>>(Hbuf, woP, te, tokr, wrr,
                                                    out, W, f0, KCH);
    } else {
      moe_g1<false><<<g1grid, 256, LDS_GX, stream>>>(Xg, wiP, te, Hbuf, W, f0);
      moe_g2<false><<<g2grid, 256, LDS_GX, stream>>>(Hbuf, woP, te, tokr, wrr,
                                                     out, W, f0, KCH);
    }
  }
}

// Round 18
// 557.206 us; speedup vs baseline: 1.0521x; 1.0521x over previous
//
#include <hip/hip_runtime.h>
#include <hip/hip_bf16.h>

// MoE Experts v17: v12 structure (best: 524us) with 2-buffer rings +
// end-of-iteration staging to double block co-residency without changing
// tile sizes: g1 256x256 @ 64KB LDS -> 2 blocks/CU; g2 256x128 @ 48KB ->
// 3 blocks/CU. Counted vmcnt (4 / 3) at loop top, stage after post-MFMA
// barrier (reads lgkm-drained before it -> no overwrite race).

#define T_TOK   8192
#define D_MODEL 1024
#define D_FF    4096
#define NE      8
#define MT2     72                 // 256-row tiles
#define ROWS_MAX (MT2 * 256)       // 18432
#define BUF1    32768              // g1: A16K + B16K
#define LDS_G1  65536              // 2 buffers
#define BUF2    24576              // g2: A16K + B8K
#define LDS_G2  49152              // 2 buffers

typedef float f32x4 __attribute__((ext_vector_type(4)));
typedef short s16x8 __attribute__((ext_vector_type(8)));
typedef short s16x4 __attribute__((ext_vector_type(4)));
typedef unsigned short u16;

__device__ __forceinline__ u16 f2bf(float x) {
  __hip_bfloat16 h = __float2bfloat16(x);   // RNE
  return *reinterpret_cast<u16*>(&h);
}

__device__ __forceinline__ s16x8 cvt8(float4 a, float4 b) {
  s16x8 v;
  v[0] = (short)f2bf(a.x); v[1] = (short)f2bf(a.y);
  v[2] = (short)f2bf(a.z); v[3] = (short)f2bf(a.w);
  v[4] = (short)f2bf(b.x); v[5] = (short)f2bf(b.y);
  v[6] = (short)f2bf(b.z); v[7] = (short)f2bf(b.w);
  return v;
}

__device__ __forceinline__ void gload_lds16(const void* g, void* l) {
  __builtin_amdgcn_global_load_lds((const __attribute__((address_space(1))) void*)g,
                                   (__attribute__((address_space(3))) void*)l,
                                   16, 0, 0);
}

// ---------------- routing compaction ----------------
__global__ void moe_route(const int* __restrict__ sel, const float* __restrict__ rw,
                          int* __restrict__ cnt, int* __restrict__ tidx,
                          float* __restrict__ tw) {
  int t = blockIdx.x * blockDim.x + threadIdx.x;
  if (t >= T_TOK) return;
  int e0 = 0, e1 = 0;
  #pragma unroll
  for (int e = 0; e < NE; ++e) {
    if (sel[t * 16 + e])     e0 = e;
    if (sel[t * 16 + 8 + e]) e1 = e;
  }
  float w0 = rw[2 * t], w1 = rw[2 * t + 1];
  if (e0 == e1) {
    int p = atomicAdd(&cnt[e0], 1);
    tidx[e0 * T_TOK + p] = t; tw[e0 * T_TOK + p] = w0 + w1;
  } else {
    int p = atomicAdd(&cnt[e0], 1);
    tidx[e0 * T_TOK + p] = t; tw[e0 * T_TOK + p] = w0;
    int q = atomicAdd(&cnt[e1], 1);
    tidx[e1 * T_TOK + q] = t; tw[e1 * T_TOK + q] = w1;
  }
}

// ---------------- tile map ----------------
__global__ void moe_tilemap(const int* __restrict__ cnt, const int* __restrict__ tidx,
                            const float* __restrict__ tw, int* __restrict__ te256,
                            int* __restrict__ tokr, float* __restrict__ wr) {
  int off[NE + 1];
  {
    int o = 0;
    #pragma unroll
    for (int e = 0; e < NE; ++e) { off[e] = o; o += (cnt[e] + 255) & ~255; }
    off[NE] = o;
  }
  const int total = off[NE];
  const int gid = blockIdx.x * blockDim.x + threadIdx.x;
  const int stride = gridDim.x * blockDim.x;
  for (int t = gid; t < MT2; t += stride) {
    int r0 = t * 256; int e = -1;
    if (r0 < total) {
      #pragma unroll
      for (int i = NE - 1; i >= 0; --i) if (r0 >= off[i]) { e = i; break; }
    }
    te256[t] = e;
  }
  for (int i = gid; i < ROWS_MAX; i += stride) {
    if (i >= total) { tokr[i] = -1; wr[i] = 0.f; continue; }
    int e = 0;
    #pragma unroll
    for (int k = NE - 1; k >= 0; --k) if (i >= off[k]) { e = k; break; }
    int j = i - off[e];
    int ok = j < cnt[e];
    tokr[i] = ok ? tidx[e * T_TOK + j] : -1;
    wr[i]   = ok ? tw[e * T_TOK + j] : 0.f;
  }
}

// ---------------- gather X rows -> bf16 Xg ----------------
__global__ void moe_gather_x(const float* __restrict__ hs, const int* __restrict__ tokr,
                             u16* __restrict__ Xg) {
  int row = blockIdx.x;
  int tok = tokr[row];
  int c = threadIdx.x * 4;
  u16* dst = Xg + (size_t)row * D_MODEL + c;
  s16x4 o;
  if (tok < 0) {
    o[0] = o[1] = o[2] = o[3] = 0;
  } else {
    float4 v = *(const float4*)(hs + (size_t)tok * D_MODEL + c);
    o[0] = (short)f2bf(v.x); o[1] = (short)f2bf(v.y);
    o[2] = (short)f2bf(v.z); o[3] = (short)f2bf(v.w);
  }
  *(s16x4*)dst = o;
}

// ---------------- f32 -> bf16 weight converts ----------------
__global__ void moe_cvt_w(const float* __restrict__ wi, const float* __restrict__ wo,
                          u16* __restrict__ wib, u16* __restrict__ wob) {
  const size_t NW = (size_t)NE * D_FF * D_MODEL;
  size_t i = ((size_t)blockIdx.x * blockDim.x + threadIdx.x) * 8;
  const float* src; u16* dst;
  if (i < NW) { src = wi + i; dst = wib + i; }
  else        { src = wo + (i - NW); dst = wob + (i - NW); }
  float4 a = *(const float4*)(src);
  float4 b = *(const float4*)(src + 4);
  *(s16x8*)dst = cvt8(a, b);
}

__global__ void moe_cvt_wi_s(const float* __restrict__ wi, u16* __restrict__ wis,
                             int W, int f0) {
  size_t i = ((size_t)blockIdx.x * blockDim.x + threadIdx.x) * 8;
  size_t per = (size_t)W * D_MODEL;
  int e = (int)(i / per); size_t r = i % per;
  const float* src = wi + ((size_t)e * D_FF + f0) * D_MODEL + r;
  float4 a = *(const float4*)src;
  float4 b = *(const float4*)(src + 4);
  *(s16x8*)(wis + i) = cvt8(a, b);
}

__global__ void moe_cvt_wo_s(const float* __restrict__ wo, u16* __restrict__ wos,
                             int W, int f0) {
  size_t i = ((size_t)blockIdx.x * blockDim.x + threadIdx.x) * 8;
  size_t per = (size_t)D_MODEL * W;
  int e = (int)(i / per); size_t r = i % per;
  int row = (int)(r / W), col = (int)(r % W);
  const float* src = wo + ((size_t)e * D_MODEL + row) * D_FF + f0 + col;
  float4 a = *(const float4*)src;
  float4 b = *(const float4*)(src + 4);
  *(s16x8*)(wos + i) = cvt8(a, b);
}

#define MM4(mi, a) \
  acc[mi][0] = __builtin_amdgcn_mfma_f32_16x16x32_bf16(a, bq0, acc[mi][0], 0, 0, 0); \
  acc[mi][1] = __builtin_amdgcn_mfma_f32_16x16x32_bf16(a, bq1, acc[mi][1], 0, 0, 0); \
  acc[mi][2] = __builtin_amdgcn_mfma_f32_16x16x32_bf16(a, bq2, acc[mi][2], 0, 0, 0); \
  acc[mi][3] = __builtin_amdgcn_mfma_f32_16x16x32_bf16(a, bq3, acc[mi][3], 0, 0, 0);

// ---------------- GEMM1: 256x256, 2-buf ring, 2 blocks/CU ----------------
template <bool FULL>
__global__ __launch_bounds__(512, 2)
void moe_g1(const u16* __restrict__ Xg, const u16* __restrict__ wiP,
            const int* __restrict__ te256, u16* __restrict__ H,
            int W, int f0) {
  extern __shared__ char lds[];
  const int GR = gridDim.x;
  const int task = (blockIdx.x & 7) * (GR >> 3) + (blockIdx.x >> 3);
  const int mt = task % MT2;
  const int nc = task / MT2;
  const int e = te256[mt];
  if (e < 0) return;
  const int grow0 = mt * 256;
  const int fcol = nc * 256;

  const int tid = threadIdx.x;
  const int lane = tid & 63, wv = tid >> 6;
  const int lg = lane >> 4, ll = lane & 15;
  const int wm = wv >> 2, wn = wv & 3;

  const int sw = (tid * 16) ^ (((tid >> 3) & 7) << 4);
  const int srow = sw >> 6, scol = sw & 63;
  const int inner = (ll * 64 + lg * 16) ^ (((ll >> 1) & 7) << 4);

  const char* gA = (const char*)(Xg + (size_t)grow0 * D_MODEL);
  const char* gB = (const char*)(wiP + (FULL ? ((size_t)e * D_FF + f0 + fcol)
                                             : ((size_t)e * W + fcol)) * D_MODEL);

  f32x4 acc[8][4];
  #pragma unroll
  for (int m = 0; m < 8; ++m)
    #pragma unroll
    for (int n = 0; n < 4; ++n) acc[m][n] = (f32x4){0.f, 0.f, 0.f, 0.f};

  auto stage = [&](int kb, char* lbuf) {
    #pragma unroll
    for (int j = 0; j < 2; ++j)
      gload_lds16(gA + (size_t)(j * 128 + srow) * 2048 + kb + scol,
                  lbuf + j * 8192 + tid * 16);
    #pragma unroll
    for (int j = 0; j < 2; ++j)
      gload_lds16(gB + (size_t)(j * 128 + srow) * 2048 + kb + scol,
                  lbuf + 16384 + j * 8192 + tid * 16);
  };

  const int NT = D_MODEL / 32;
  stage(0, lds);
  stage(64, lds + BUF1);
  for (int t = 0; t < NT; ++t) {
    if (t < NT - 1) { asm volatile("s_waitcnt vmcnt(4)" ::: "memory"); }
    else            { asm volatile("s_waitcnt vmcnt(0)" ::: "memory"); }
    asm volatile("s_barrier" ::: "memory");
    char* lbuf = lds + (t & 1) * BUF1;
    const char* la = lbuf + wm * 8192;
    const char* lb = lbuf + 16384 + wn * 4096;
    s16x8 bq0 = *(const s16x8*)(lb + 0 * 1024 + inner);
    s16x8 bq1 = *(const s16x8*)(lb + 1 * 1024 + inner);
    s16x8 bq2 = *(const s16x8*)(lb + 2 * 1024 + inner);
    s16x8 bq3 = *(const s16x8*)(lb + 3 * 1024 + inner);
    {
      s16x8 a0 = *(const s16x8*)(la + 0 * 1024 + inner);
      s16x8 a1 = *(const s16x8*)(la + 1 * 1024 + inner);
      s16x8 a2 = *(const s16x8*)(la + 2 * 1024 + inner);
      s16x8 a3 = *(const s16x8*)(la + 3 * 1024 + inner);
      __builtin_amdgcn_s_setprio(1);
      MM4(0, a0) MM4(1, a1) MM4(2, a2) MM4(3, a3)
      __builtin_amdgcn_s_setprio(0);
    }
    {
      s16x8 a0 = *(const s16x8*)(la + 4 * 1024 + inner);
      s16x8 a1 = *(const s16x8*)(la + 5 * 1024 + inner);
      s16x8 a2 = *(const s16x8*)(la + 6 * 1024 + inner);
      s16x8 a3 = *(const s16x8*)(la + 7 * 1024 + inner);
      __builtin_amdgcn_s_setprio(1);
      MM4(4, a0) MM4(5, a1) MM4(6, a2) MM4(7, a3)
      __builtin_amdgcn_s_setprio(0);
    }
    // all ds_reads above are consumed (lgkm-drained) before this barrier
    asm volatile("s_barrier" ::: "memory");
    if (t + 2 < NT) stage((t + 2) * 64, lbuf);   // overwrite own (drained) buf
  }

  #pragma unroll
  for (int mf = 0; mf < 8; ++mf) {
    #pragma unroll
    for (int r = 0; r < 4; ++r) {
      int row = grow0 + wm * 128 + mf * 16 + lg * 4 + r;
      u16* hp = H + (size_t)row * W + fcol + wn * 64 + ll;
      #pragma unroll
      for (int nf = 0; nf < 4; ++nf) {
        float v = acc[mf][nf][r];
        hp[nf * 16] = f2bf(v > 0.f ? v : 0.f);
      }
    }
  }
}

// ---------------- GEMM2: 256x128, 2-buf ring, 3 blocks/CU ----------------
template <bool FULL>
__global__ __launch_bounds__(512, 3)
void moe_g2(const u16* __restrict__ H, const u16* __restrict__ woP,
            const int* __restrict__ te256, const int* __restrict__ tokr,
            const float* __restrict__ wr, float* __restrict__ out,
            int W, int f0, int KCH) {
  extern __shared__ char lds[];
  const int GR = gridDim.x;
  const int task = (blockIdx.x & 7) * (GR >> 3) + (blockIdx.x >> 3);
  const int dc = task & 7;
  const int rest = task >> 3;
  const int mt = rest % MT2;
  const int kc = rest / MT2;
  const int e = te256[mt];
  if (e < 0) return;
  const int grow0 = mt * 256;
  const int dcol0 = dc * 128;

  const int tid = threadIdx.x;
  const int lane = tid & 63, wv = tid >> 6;
  const int lg = lane >> 4, ll = lane & 15;
  const int wm = wv >> 1, wn = wv & 1;

  const int sw = (tid * 16) ^ (((tid >> 3) & 7) << 4);
  const int srow = sw >> 6, scol = sw & 63;
  const int inner = (ll * 64 + lg * 16) ^ (((ll >> 1) & 7) << 4);

  const size_t pA = (size_t)W * 2;
  const size_t pB = (FULL ? (size_t)D_FF : (size_t)W) * 2;
  const char* gA = (const char*)(H + (size_t)grow0 * W) + (size_t)kc * KCH * 2;
  const char* gB = (const char*)(woP + ((size_t)e * D_MODEL + dcol0) * (pB / 2)
                                 + (FULL ? f0 : 0)) + (size_t)kc * KCH * 2;

  f32x4 acc[4][4];
  #pragma unroll
  for (int m = 0; m < 4; ++m)
    #pragma unroll
    for (int n = 0; n < 4; ++n) acc[m][n] = (f32x4){0.f, 0.f, 0.f, 0.f};

  auto stage = [&](int kb, char* lbuf) {
    #pragma unroll
    for (int j = 0; j < 2; ++j)
      gload_lds16(gA + (size_t)(j * 128 + srow) * pA + kb + scol,
                  lbuf + j * 8192 + tid * 16);
    gload_lds16(gB + (size_t)srow * pB + kb + scol, lbuf + 16384 + tid * 16);
  };

  const int NT = KCH / 32;
  stage(0, lds);
  stage(64, lds + BUF2);
  for (int t = 0; t < NT; ++t) {
    if (t < NT - 1) { asm volatile("s_waitcnt vmcnt(3)" ::: "memory"); }
    else            { asm volatile("s_waitcnt vmcnt(0)" ::: "memory"); }
    asm volatile("s_barrier" ::: "memory");
    char* lbuf = lds + (t & 1) * BUF2;
    const char* la = lbuf + wm * 4096;
    const char* lb = lbuf + 16384 + wn * 4096;
    s16x8 bq0 = *(const s16x8*)(lb + 0 * 1024 + inner);
    s16x8 bq1 = *(const s16x8*)(lb + 1 * 1024 + inner);
    s16x8 bq2 = *(const s16x8*)(lb + 2 * 1024 + inner);
    s16x8 bq3 = *(const s16x8*)(lb + 3 * 1024 + inner);
    {
      s16x8 a0 = *(const s16x8*)(la + 0 * 1024 + inner);
      s16x8 a1 = *(const s16x8*)(la + 1 * 1024 + inner);
      __builtin_amdgcn_s_setprio(1);
      MM4(0, a0) MM4(1, a1)
      __builtin_amdgcn_s_setprio(0);
    }
    {
      s16x8 a2 = *(const s16x8*)(la + 2 * 1024 + inner);
      s16x8 a3 = *(const s16x8*)(la + 3 * 1024 + inner);
      __builtin_amdgcn_s_setprio(1);
      MM4(2, a2) MM4(3, a3)
      __builtin_amdgcn_s_setprio(0);
    }
    asm volatile("s_barrier" ::: "memory");
    if (t + 2 < NT) stage((t + 2) * 64, lbuf);
  }

  #pragma unroll
  for (int mf = 0; mf < 4; ++mf) {
    #pragma unroll
    for (int r = 0; r < 4; ++r) {
      int row = grow0 + wm * 64 + mf * 16 + lg * 4 + r;
      int tok = tokr[row];
      if (tok >= 0) {
        float w = wr[row];
        float* op = out + (size_t)tok * D_MODEL + dcol0 + wn * 64 + ll;
        #pragma unroll
        for (int nf = 0; nf < 4; ++nf)
          atomicAdd(op + nf * 16, acc[mf][nf][r] * w);
      }
    }
  }
}

// ---------------- host ----------------
extern "C" void kernel_launch(void* const* d_in, const int* in_sizes, int n_in,
                              void* d_out, int out_size, void* d_ws, size_t ws_size,
                              hipStream_t stream) {
  const float* hs  = (const float*)d_in[0];
  const int*   sel = (const int*)d_in[1];
  const float* rw  = (const float*)d_in[2];
  const float* wi  = (const float*)d_in[3];
  const float* wo  = (const float*)d_in[4];
  float* out = (float*)d_out;

  const size_t NW   = (size_t)NE * D_FF * D_MODEL;
  const size_t CTRL = 1u << 20;
  const size_t WB   = 2 * NW * sizeof(u16);
  const size_t XGB  = (size_t)ROWS_MAX * D_MODEL * 2;

  bool FULLW = true; int W = D_FF;
  {
    bool found = false;
    for (int f : {1, 2, 4, 8, 16}) {
      int Wc = D_FF / f;
      size_t need = CTRL + WB + XGB + (size_t)ROWS_MAX * Wc * 2;
      if (need <= ws_size) { FULLW = true; W = Wc; found = true; break; }
    }
    if (!found) {
      for (int Wc : {1024, 512, 256}) {
        size_t sl = (size_t)2 * NE * Wc * D_MODEL * 2;
        size_t need = CTRL + sl + XGB + (size_t)ROWS_MAX * Wc * 2;
        if (need <= ws_size) { FULLW = false; W = Wc; break; }
      }
    }
  }
  const int FS = D_FF / W;

  size_t off = 0;
  auto take = [&](size_t b) -> char* {
    char* r = (char*)d_ws + off; off = (off + b + 255) & ~(size_t)255; return r;
  };
  int*   tidx = (int*)take((size_t)NE * T_TOK * 4);
  float* tw   = (float*)take((size_t)NE * T_TOK * 4);
  int*   tokr = (int*)take((size_t)ROWS_MAX * 4);
  float* wrr  = (float*)take((size_t)ROWS_MAX * 4);
  int*   te2  = (int*)take(MT2 * 4);
  int*   cnt  = (int*)take(256);
  off = CTRL;
  u16 *wiP, *woP;
  if (FULLW) { wiP = (u16*)take(NW * 2); woP = (u16*)take(NW * 2); }
  else       { wiP = (u16*)take((size_t)NE * W * D_MODEL * 2);
               woP = (u16*)take((size_t)NE * D_MODEL * W * 2); }
  u16* Xg   = (u16*)take(XGB);
  u16* Hbuf = (u16*)take((size_t)ROWS_MAX * W * 2);

  hipMemsetAsync(cnt, 0, 256, stream);
  hipMemsetAsync(d_out, 0, (size_t)out_size * sizeof(float), stream);
  moe_route<<<T_TOK / 256, 256, 0, stream>>>(sel, rw, cnt, tidx, tw);
  moe_tilemap<<<64, 256, 0, stream>>>(cnt, tidx, tw, te2, tokr, wrr);
  moe_gather_x<<<ROWS_MAX, 256, 0, stream>>>(hs, tokr, Xg);
  if (FULLW)
    moe_cvt_w<<<(int)(2 * NW / 8 / 256), 256, 0, stream>>>(wi, wo, wiP, woP);

  hipFuncSetAttribute(reinterpret_cast<const void*>(&moe_g1<true>),
                      hipFuncAttributeMaxDynamicSharedMemorySize, LDS_G1);
  hipFuncSetAttribute(reinterpret_cast<const void*>(&moe_g1<false>),
                      hipFuncAttributeMaxDynamicSharedMemorySize, LDS_G1);
  hipFuncSetAttribute(reinterpret_cast<const void*>(&moe_g2<true>),
                      hipFuncAttributeMaxDynamicSharedMemorySize, LDS_G2);
  hipFuncSetAttribute(reinterpret_cast<const void*>(&moe_g2<false>),
                      hipFuncAttributeMaxDynamicSharedMemorySize, LDS_G2);

  const int KCH = W / 2;
  const int g1grid = MT2 * (W / 256);             // 1152 at FS=1
  const int g2grid = MT2 * 8 * 2;                 // 1152
  const int cvtblk = (int)(((size_t)NE * W * D_MODEL / 8) / 256);

  for (int p = 0; p < FS; ++p) {
    const int f0 = p * W;
    if (!FULLW) {
      moe_cvt_wi_s<<<cvtblk, 256, 0, stream>>>(wi, wiP, W, f0);
      moe_cvt_wo_s<<<cvtblk, 256, 0, stream>>>(wo, woP, W, f0);
    }
    if (FULLW) {
      moe_g1<true><<<g1grid, 512, LDS_G1, stream>>>(Xg, wiP, te2, Hbuf, W, f0);
      moe_g2<true><<<g2grid, 512, LDS_G2, stream>>>(Hbuf, woP, te2, tokr, wrr,
                                                    out, W, f0, KCH);
    } else {
      moe_g1<false><<<g1grid, 512, LDS_G1, stream>>>(Xg, wiP, te2, Hbuf, W, f0);
      moe_g2<false><<<g2grid, 512, LDS_G2, stream>>>(Hbuf, woP, te2, tokr, wrr,
                                                     out, W, f0, KCH);
    }
  }
}

// Round 19
// 524.587 us; speedup vs baseline: 1.1176x; 1.0622x over previous
//
#include <hip/hip_runtime.h>
#include <hip/hip_bf16.h>

// MoE Experts v18 = v12 restored verbatim (best measured: 524us).
// g1: 256x256 deep-pipe, 3x32KB LDS ring, counted vmcnt(4), de-lockstepped
// (no mid barrier), setprio. g2: 256x128, 3x24KB ring, vmcnt(3), 2 blk/CU,
// dc-innermost task order (H L2 reuse), f32 atomic scatter.
// Campaign ledger: v13 per-phase-wait 533 | v15 T4-exact 533 | v16 128^2 586
// | v17 2-buf 557 | v10 256^2-g2 663 -> v12's 524 is the family optimum.

#define T_TOK   8192
#define D_MODEL 1024
#define D_FF    4096
#define NE      8
#define MT2     72                 // 256-row tiles
#define ROWS_MAX (MT2 * 256)       // 18432
#define BUFB    32768              // g1 buffer stride (A16K+B16K)
#define LDS_G1  98304
#define BUF2    24576              // g2 buffer stride (A16K+B8K)
#define LDS_G2  73728

typedef float f32x4 __attribute__((ext_vector_type(4)));
typedef short s16x8 __attribute__((ext_vector_type(8)));
typedef short s16x4 __attribute__((ext_vector_type(4)));
typedef unsigned short u16;

__device__ __forceinline__ u16 f2bf(float x) {
  __hip_bfloat16 h = __float2bfloat16(x);   // RNE
  return *reinterpret_cast<u16*>(&h);
}

__device__ __forceinline__ s16x8 cvt8(float4 a, float4 b) {
  s16x8 v;
  v[0] = (short)f2bf(a.x); v[1] = (short)f2bf(a.y);
  v[2] = (short)f2bf(a.z); v[3] = (short)f2bf(a.w);
  v[4] = (short)f2bf(b.x); v[5] = (short)f2bf(b.y);
  v[6] = (short)f2bf(b.z); v[7] = (short)f2bf(b.w);
  return v;
}

__device__ __forceinline__ void gload_lds16(const void* g, void* l) {
  __builtin_amdgcn_global_load_lds((const __attribute__((address_space(1))) void*)g,
                                   (__attribute__((address_space(3))) void*)l,
                                   16, 0, 0);
}

// ---------------- routing compaction ----------------
__global__ void moe_route(const int* __restrict__ sel, const float* __restrict__ rw,
                          int* __restrict__ cnt, int* __restrict__ tidx,
                          float* __restrict__ tw) {
  int t = blockIdx.x * blockDim.x + threadIdx.x;
  if (t >= T_TOK) return;
  int e0 = 0, e1 = 0;
  #pragma unroll
  for (int e = 0; e < NE; ++e) {
    if (sel[t * 16 + e])     e0 = e;
    if (sel[t * 16 + 8 + e]) e1 = e;
  }
  float w0 = rw[2 * t], w1 = rw[2 * t + 1];
  if (e0 == e1) {
    int p = atomicAdd(&cnt[e0], 1);
    tidx[e0 * T_TOK + p] = t; tw[e0 * T_TOK + p] = w0 + w1;
  } else {
    int p = atomicAdd(&cnt[e0], 1);
    tidx[e0 * T_TOK + p] = t; tw[e0 * T_TOK + p] = w0;
    int q = atomicAdd(&cnt[e1], 1);
    tidx[e1 * T_TOK + q] = t; tw[e1 * T_TOK + q] = w1;
  }
}

// ---------------- tile map: 256-aligned per-expert segments ----------------
__global__ void moe_tilemap(const int* __restrict__ cnt, const int* __restrict__ tidx,
                            const float* __restrict__ tw, int* __restrict__ te256,
                            int* __restrict__ tokr, float* __restrict__ wr) {
  int off[NE + 1];
  {
    int o = 0;
    #pragma unroll
    for (int e = 0; e < NE; ++e) { off[e] = o; o += (cnt[e] + 255) & ~255; }
    off[NE] = o;
  }
  const int total = off[NE];
  const int gid = blockIdx.x * blockDim.x + threadIdx.x;
  const int stride = gridDim.x * blockDim.x;
  for (int t = gid; t < MT2; t += stride) {
    int r0 = t * 256; int e = -1;
    if (r0 < total) {
      #pragma unroll
      for (int i = NE - 1; i >= 0; --i) if (r0 >= off[i]) { e = i; break; }
    }
    te256[t] = e;
  }
  for (int i = gid; i < ROWS_MAX; i += stride) {
    if (i >= total) { tokr[i] = -1; wr[i] = 0.f; continue; }
    int e = 0;
    #pragma unroll
    for (int k = NE - 1; k >= 0; --k) if (i >= off[k]) { e = k; break; }
    int j = i - off[e];
    int ok = j < cnt[e];
    tokr[i] = ok ? tidx[e * T_TOK + j] : -1;
    wr[i]   = ok ? tw[e * T_TOK + j] : 0.f;
  }
}

// ---------------- gather X rows -> bf16 Xg ----------------
__global__ void moe_gather_x(const float* __restrict__ hs, const int* __restrict__ tokr,
                             u16* __restrict__ Xg) {
  int row = blockIdx.x;
  int tok = tokr[row];
  int c = threadIdx.x * 4;
  u16* dst = Xg + (size_t)row * D_MODEL + c;
  s16x4 o;
  if (tok < 0) {
    o[0] = o[1] = o[2] = o[3] = 0;
  } else {
    float4 v = *(const float4*)(hs + (size_t)tok * D_MODEL + c);
    o[0] = (short)f2bf(v.x); o[1] = (short)f2bf(v.y);
    o[2] = (short)f2bf(v.z); o[3] = (short)f2bf(v.w);
  }
  *(s16x4*)dst = o;
}

// ---------------- f32 -> bf16 weight converts ----------------
__global__ void moe_cvt_w(const float* __restrict__ wi, const float* __restrict__ wo,
                          u16* __restrict__ wib, u16* __restrict__ wob) {
  const size_t NW = (size_t)NE * D_FF * D_MODEL;
  size_t i = ((size_t)blockIdx.x * blockDim.x + threadIdx.x) * 8;
  const float* src; u16* dst;
  if (i < NW) { src = wi + i; dst = wib + i; }
  else        { src = wo + (i - NW); dst = wob + (i - NW); }
  float4 a = *(const float4*)(src);
  float4 b = *(const float4*)(src + 4);
  *(s16x8*)dst = cvt8(a, b);
}

__global__ void moe_cvt_wi_s(const float* __restrict__ wi, u16* __restrict__ wis,
                             int W, int f0) {
  size_t i = ((size_t)blockIdx.x * blockDim.x + threadIdx.x) * 8;
  size_t per = (size_t)W * D_MODEL;
  int e = (int)(i / per); size_t r = i % per;
  const float* src = wi + ((size_t)e * D_FF + f0) * D_MODEL + r;
  float4 a = *(const float4*)src;
  float4 b = *(const float4*)(src + 4);
  *(s16x8*)(wis + i) = cvt8(a, b);
}

__global__ void moe_cvt_wo_s(const float* __restrict__ wo, u16* __restrict__ wos,
                             int W, int f0) {
  size_t i = ((size_t)blockIdx.x * blockDim.x + threadIdx.x) * 8;
  size_t per = (size_t)D_MODEL * W;
  int e = (int)(i / per); size_t r = i % per;
  int row = (int)(r / W), col = (int)(r % W);
  const float* src = wo + ((size_t)e * D_MODEL + row) * D_FF + f0 + col;
  float4 a = *(const float4*)src;
  float4 b = *(const float4*)(src + 4);
  *(s16x8*)(wos + i) = cvt8(a, b);
}

#define MM4(mi, a) \
  acc[mi][0] = __builtin_amdgcn_mfma_f32_16x16x32_bf16(a, bq0, acc[mi][0], 0, 0, 0); \
  acc[mi][1] = __builtin_amdgcn_mfma_f32_16x16x32_bf16(a, bq1, acc[mi][1], 0, 0, 0); \
  acc[mi][2] = __builtin_amdgcn_mfma_f32_16x16x32_bf16(a, bq2, acc[mi][2], 0, 0, 0); \
  acc[mi][3] = __builtin_amdgcn_mfma_f32_16x16x32_bf16(a, bq3, acc[mi][3], 0, 0, 0);

// ---------------- GEMM1: 256x256 deep-pipe, de-lockstepped ----------------
template <bool FULL>
__global__ __launch_bounds__(512, 1)
void moe_g1(const u16* __restrict__ Xg, const u16* __restrict__ wiP,
            const int* __restrict__ te256, u16* __restrict__ H,
            int W, int f0) {
  extern __shared__ char lds[];
  const int GR = gridDim.x;
  const int task = (blockIdx.x & 7) * (GR >> 3) + (blockIdx.x >> 3);
  const int mt = task % MT2;
  const int nc = task / MT2;
  const int e = te256[mt];
  if (e < 0) return;
  const int grow0 = mt * 256;
  const int fcol = nc * 256;

  const int tid = threadIdx.x;
  const int lane = tid & 63, wv = tid >> 6;
  const int lg = lane >> 4, ll = lane & 15;
  const int wm = wv >> 2, wn = wv & 3;

  const int sw = (tid * 16) ^ (((tid >> 3) & 7) << 4);
  const int srow = sw >> 6, scol = sw & 63;
  const int inner = (ll * 64 + lg * 16) ^ (((ll >> 1) & 7) << 4);

  const char* gA = (const char*)(Xg + (size_t)grow0 * D_MODEL);
  const char* gB = (const char*)(wiP + (FULL ? ((size_t)e * D_FF + f0 + fcol)
                                             : ((size_t)e * W + fcol)) * D_MODEL);

  f32x4 acc[8][4];
  #pragma unroll
  for (int m = 0; m < 8; ++m)
    #pragma unroll
    for (int n = 0; n < 4; ++n) acc[m][n] = (f32x4){0.f, 0.f, 0.f, 0.f};

  auto stageA = [&](int kb, char* lbuf) {
    #pragma unroll
    for (int j = 0; j < 2; ++j)
      gload_lds16(gA + (size_t)(j * 128 + srow) * 2048 + kb + scol,
                  lbuf + j * 8192 + tid * 16);
  };
  auto stageB = [&](int kb, char* lbuf) {
    #pragma unroll
    for (int j = 0; j < 2; ++j)
      gload_lds16(gB + (size_t)(j * 128 + srow) * 2048 + kb + scol,
                  lbuf + 16384 + j * 8192 + tid * 16);
  };

  const int NT = D_MODEL / 32;                 // 32 K-tiles of BK=32
  stageA(0, lds);   stageB(0, lds);
  stageA(64, lds + BUFB); stageB(64, lds + BUFB);
  int bufi = 0;
  for (int t = 0; t < NT; ++t) {
    if (t < NT - 1) { asm volatile("s_waitcnt vmcnt(4)" ::: "memory"); }
    else            { asm volatile("s_waitcnt vmcnt(0)" ::: "memory"); }
    asm volatile("s_barrier" ::: "memory");
    const char* la = lds + bufi * BUFB + wm * 8192;
    const char* lb = lds + bufi * BUFB + 16384 + wn * 4096;
    int b2 = bufi + 2; if (b2 >= 3) b2 -= 3;
    const bool pf = (t + 2 < NT);
    s16x8 bq0 = *(const s16x8*)(lb + 0 * 1024 + inner);
    s16x8 bq1 = *(const s16x8*)(lb + 1 * 1024 + inner);
    s16x8 bq2 = *(const s16x8*)(lb + 2 * 1024 + inner);
    s16x8 bq3 = *(const s16x8*)(lb + 3 * 1024 + inner);
    {
      s16x8 a0 = *(const s16x8*)(la + 0 * 1024 + inner);
      s16x8 a1 = *(const s16x8*)(la + 1 * 1024 + inner);
      s16x8 a2 = *(const s16x8*)(la + 2 * 1024 + inner);
      s16x8 a3 = *(const s16x8*)(la + 3 * 1024 + inner);
      if (pf) stageA((t + 2) * 64, lds + b2 * BUFB);
      __builtin_amdgcn_s_setprio(1);
      MM4(0, a0) MM4(1, a1) MM4(2, a2) MM4(3, a3)
      __builtin_amdgcn_s_setprio(0);
    }
    {
      s16x8 a0 = *(const s16x8*)(la + 4 * 1024 + inner);
      s16x8 a1 = *(const s16x8*)(la + 5 * 1024 + inner);
      s16x8 a2 = *(const s16x8*)(la + 6 * 1024 + inner);
      s16x8 a3 = *(const s16x8*)(la + 7 * 1024 + inner);
      if (pf) stageB((t + 2) * 64, lds + b2 * BUFB);
      __builtin_amdgcn_s_setprio(1);
      MM4(4, a0) MM4(5, a1) MM4(6, a2) MM4(7, a3)
      __builtin_amdgcn_s_setprio(0);
    }
    bufi += 1; if (bufi >= 3) bufi -= 3;
  }

  #pragma unroll
  for (int mf = 0; mf < 8; ++mf) {
    #pragma unroll
    for (int r = 0; r < 4; ++r) {
      int row = grow0 + wm * 128 + mf * 16 + lg * 4 + r;
      u16* hp = H + (size_t)row * W + fcol + wn * 64 + ll;
      #pragma unroll
      for (int nf = 0; nf < 4; ++nf) {
        float v = acc[mf][nf][r];
        hp[nf * 16] = f2bf(v > 0.f ? v : 0.f);
      }
    }
  }
}

// ---------------- GEMM2: 256x128 deep-pipe, de-lockstepped ----------------
template <bool FULL>
__global__ __launch_bounds__(512, 4)
void moe_g2(const u16* __restrict__ H, const u16* __restrict__ woP,
            const int* __restrict__ te256, const int* __restrict__ tokr,
            const float* __restrict__ wr, float* __restrict__ out,
            int W, int f0, int KCH) {
  extern __shared__ char lds[];
  const int GR = gridDim.x;
  const int task = (blockIdx.x & 7) * (GR >> 3) + (blockIdx.x >> 3);
  const int dc = task & 7;
  const int rest = task >> 3;
  const int mt = rest % MT2;
  const int kc = rest / MT2;
  const int e = te256[mt];
  if (e < 0) return;
  const int grow0 = mt * 256;
  const int dcol0 = dc * 128;

  const int tid = threadIdx.x;
  const int lane = tid & 63, wv = tid >> 6;
  const int lg = lane >> 4, ll = lane & 15;
  const int wm = wv >> 1, wn = wv & 1;

  const int sw = (tid * 16) ^ (((tid >> 3) & 7) << 4);
  const int srow = sw >> 6, scol = sw & 63;
  const int inner = (ll * 64 + lg * 16) ^ (((ll >> 1) & 7) << 4);

  const size_t pA = (size_t)W * 2;
  const size_t pB = (FULL ? (size_t)D_FF : (size_t)W) * 2;
  const char* gA = (const char*)(H + (size_t)grow0 * W) + (size_t)kc * KCH * 2;
  const char* gB = (const char*)(woP + ((size_t)e * D_MODEL + dcol0) * (pB / 2)
                                 + (FULL ? f0 : 0)) + (size_t)kc * KCH * 2;

  f32x4 acc[4][4];
  #pragma unroll
  for (int m = 0; m < 4; ++m)
    #pragma unroll
    for (int n = 0; n < 4; ++n) acc[m][n] = (f32x4){0.f, 0.f, 0.f, 0.f};

  auto stageA = [&](int kb, char* lbuf) {
    #pragma unroll
    for (int j = 0; j < 2; ++j)
      gload_lds16(gA + (size_t)(j * 128 + srow) * pA + kb + scol,
                  lbuf + j * 8192 + tid * 16);
  };
  auto stageB = [&](int kb, char* lbuf) {
    gload_lds16(gB + (size_t)srow * pB + kb + scol, lbuf + 16384 + tid * 16);
  };

  const int NT = KCH / 32;
  stageA(0, lds);   stageB(0, lds);
  stageA(64, lds + BUF2); stageB(64, lds + BUF2);
  int bufi = 0;
  for (int t = 0; t < NT; ++t) {
    if (t < NT - 1) { asm volatile("s_waitcnt vmcnt(3)" ::: "memory"); }
    else            { asm volatile("s_waitcnt vmcnt(0)" ::: "memory"); }
    asm volatile("s_barrier" ::: "memory");
    const char* la = lds + bufi * BUF2 + wm * 4096;
    const char* lb = lds + bufi * BUF2 + 16384 + wn * 4096;
    int b2 = bufi + 2; if (b2 >= 3) b2 -= 3;
    const bool pf = (t + 2 < NT);
    s16x8 bq0 = *(const s16x8*)(lb + 0 * 1024 + inner);
    s16x8 bq1 = *(const s16x8*)(lb + 1 * 1024 + inner);
    s16x8 bq2 = *(const s16x8*)(lb + 2 * 1024 + inner);
    s16x8 bq3 = *(const s16x8*)(lb + 3 * 1024 + inner);
    {
      s16x8 a0 = *(const s16x8*)(la + 0 * 1024 + inner);
      s16x8 a1 = *(const s16x8*)(la + 1 * 1024 + inner);
      if (pf) stageA((t + 2) * 64, lds + b2 * BUF2);
      __builtin_amdgcn_s_setprio(1);
      MM4(0, a0) MM4(1, a1)
      __builtin_amdgcn_s_setprio(0);
    }
    {
      s16x8 a2 = *(const s16x8*)(la + 2 * 1024 + inner);
      s16x8 a3 = *(const s16x8*)(la + 3 * 1024 + inner);
      if (pf) stageB((t + 2) * 64, lds + b2 * BUF2);
      __builtin_amdgcn_s_setprio(1);
      MM4(2, a2) MM4(3, a3)
      __builtin_amdgcn_s_setprio(0);
    }
    bufi += 1; if (bufi >= 3) bufi -= 3;
  }

  #pragma unroll
  for (int mf = 0; mf < 4; ++mf) {
    #pragma unroll
    for (int r = 0; r < 4; ++r) {
      int row = grow0 + wm * 64 + mf * 16 + lg * 4 + r;
      int tok = tokr[row];
      if (tok >= 0) {
        float w = wr[row];
        float* op = out + (size_t)tok * D_MODEL + dcol0 + wn * 64 + ll;
        #pragma unroll
        for (int nf = 0; nf < 4; ++nf)
          atomicAdd(op + nf * 16, acc[mf][nf][r] * w);
      }
    }
  }
}

// ---------------- host ----------------
extern "C" void kernel_launch(void* const* d_in, const int* in_sizes, int n_in,
                              void* d_out, int out_size, void* d_ws, size_t ws_size,
                              hipStream_t stream) {
  const float* hs  = (const float*)d_in[0];
  const int*   sel = (const int*)d_in[1];
  const float* rw  = (const float*)d_in[2];
  const float* wi  = (const float*)d_in[3];
  const float* wo  = (const float*)d_in[4];
  float* out = (float*)d_out;

  const size_t NW   = (size_t)NE * D_FF * D_MODEL;
  const size_t CTRL = 1u << 20;
  const size_t WB   = 2 * NW * sizeof(u16);
  const size_t XGB  = (size_t)ROWS_MAX * D_MODEL * 2;

  bool FULLW = true; int W = D_FF;
  {
    bool found = false;
    for (int f : {1, 2, 4, 8, 16}) {
      int Wc = D_FF / f;
      size_t need = CTRL + WB + XGB + (size_t)ROWS_MAX * Wc * 2;
      if (need <= ws_size) { FULLW = true; W = Wc; found = true; break; }
    }
    if (!found) {
      for (int Wc : {1024, 512, 256}) {
        size_t sl = (size_t)2 * NE * Wc * D_MODEL * 2;
        size_t need = CTRL + sl + XGB + (size_t)ROWS_MAX * Wc * 2;
        if (need <= ws_size) { FULLW = false; W = Wc; break; }
      }
    }
  }
  const int FS = D_FF / W;

  size_t off = 0;
  auto take = [&](size_t b) -> char* {
    char* r = (char*)d_ws + off; off = (off + b + 255) & ~(size_t)255; return r;
  };
  int*   tidx = (int*)take((size_t)NE * T_TOK * 4);
  float* tw   = (float*)take((size_t)NE * T_TOK * 4);
  int*   tokr = (int*)take((size_t)ROWS_MAX * 4);
  float* wrr  = (float*)take((size_t)ROWS_MAX * 4);
  int*   te2  = (int*)take(MT2 * 4);
  int*   cnt  = (int*)take(256);
  off = CTRL;
  u16 *wiP, *woP;
  if (FULLW) { wiP = (u16*)take(NW * 2); woP = (u16*)take(NW * 2); }
  else       { wiP = (u16*)take((size_t)NE * W * D_MODEL * 2);
               woP = (u16*)take((size_t)NE * D_MODEL * W * 2); }
  u16* Xg   = (u16*)take(XGB);
  u16* Hbuf = (u16*)take((size_t)ROWS_MAX * W * 2);

  hipMemsetAsync(cnt, 0, 256, stream);
  hipMemsetAsync(d_out, 0, (size_t)out_size * sizeof(float), stream);
  moe_route<<<T_TOK / 256, 256, 0, stream>>>(sel, rw, cnt, tidx, tw);
  moe_tilemap<<<64, 256, 0, stream>>>(cnt, tidx, tw, te2, tokr, wrr);
  moe_gather_x<<<ROWS_MAX, 256, 0, stream>>>(hs, tokr, Xg);
  if (FULLW)
    moe_cvt_w<<<(int)(2 * NW / 8 / 256), 256, 0, stream>>>(wi, wo, wiP, woP);

  hipFuncSetAttribute(reinterpret_cast<const void*>(&moe_g1<true>),
                      hipFuncAttributeMaxDynamicSharedMemorySize, LDS_G1);
  hipFuncSetAttribute(reinterpret_cast<const void*>(&moe_g1<false>),
                      hipFuncAttributeMaxDynamicSharedMemorySize, LDS_G1);
  hipFuncSetAttribute(reinterpret_cast<const void*>(&moe_g2<true>),
                      hipFuncAttributeMaxDynamicSharedMemorySize, LDS_G2);
  hipFuncSetAttribute(reinterpret_cast<const void*>(&moe_g2<false>),
                      hipFuncAttributeMaxDynamicSharedMemorySize, LDS_G2);

  const int KCH = W / 2;
  const int g1grid = MT2 * (W / 256);
  const int g2grid = MT2 * 8 * 2;
  const int cvtblk = (int)(((size_t)NE * W * D_MODEL / 8) / 256);

  for (int p = 0; p < FS; ++p) {
    const int f0 = p * W;
    if (!FULLW) {
      moe_cvt_wi_s<<<cvtblk, 256, 0, stream>>>(wi, wiP, W, f0);
      moe_cvt_wo_s<<<cvtblk, 256, 0, stream>>>(wo, woP, W, f0);
    }
    if (FULLW) {
      moe_g1<true><<<g1grid, 512, LDS_G1, stream>>>(Xg, wiP, te2, Hbuf, W, f0);
      moe_g2<true><<<g2grid, 512, LDS_G2, stream>>>(Hbuf, woP, te2, tokr, wrr,
                                                    out, W, f0, KCH);
    } else {
      moe_g1<false><<<g1grid, 512, LDS_G1, stream>>>(Xg, wiP, te2, Hbuf, W, f0);
      moe_g2<false><<<g2grid, 512, LDS_G2, stream>>>(Hbuf, woP, te2, tokr, wrr,
                                                     out, W, f0, KCH);
    }
  }
}